// Round 4
// baseline (297.113 us; speedup 1.0000x reference)
//
#include <hip/hip_runtime.h>
#include <hip/hip_bf16.h>
#include <math.h>

#define D_MODEL 1024
#define HS 2048
#define HE 1024
#define NEXP 8
#define NTOK 4096
#define NSLOT 8192

typedef __attribute__((ext_vector_type(4))) float f32x4;
typedef __attribute__((ext_vector_type(8))) short bf16x8;

__device__ __forceinline__ short f2b(float f) {
  __hip_bfloat16 h = __float2bfloat16(f);
  return *reinterpret_cast<short*>(&h);
}
__device__ __forceinline__ float b2f(short s) {
  return __bfloat162float(*reinterpret_cast<__hip_bfloat16*>(&s));
}

__device__ __forceinline__ void gl_lds16(const short* g, short* l) {
  __builtin_amdgcn_global_load_lds(
      (const __attribute__((address_space(1))) void*)g,
      (__attribute__((address_space(3))) void*)l, 16, 0, 0);
}

// ---------------- converts ----------------
__global__ __launch_bounds__(256) void cvt_x_kernel(const float* __restrict__ in,
                                                    short* __restrict__ out) {
  int i = blockIdx.x * 256 + threadIdx.x;  // over NTOK*D/4
  const float4 v = ((const float4*)in)[i];
  short4 o;
  o.x = f2b(v.x); o.y = f2b(v.y); o.z = f2b(v.z); o.w = f2b(v.w);
  ((short4*)out)[i] = o;
}

// in [R][C] f32 -> out bf16 transposed. RMAP: 0 plain [C][R]; 1/2: w13I
// interleaved row remap: out_row = (c>>5)*64 + (RMAP==2?32:0) + (c&31).
template <int RMAP>
__global__ __launch_bounds__(256) void transpose_cvt(const float* __restrict__ in,
                                                     short* __restrict__ out,
                                                     int R, int C) {
  __shared__ float tile[64][69];  // tile[col][row]
  const int t = threadIdx.x;
  const int c0 = blockIdx.x * 64;
  const int r0 = blockIdx.y * 64;
  const size_t bo = (size_t)blockIdx.z * R * C;
  const int lr = t >> 4;          // 0..15
  const int lc4 = (t & 15) * 4;   // 0..60
#pragma unroll
  for (int i = 0; i < 4; i++) {
    const float4 v = *(const float4*)&in[bo + (size_t)(r0 + lr + i * 16) * C + c0 + lc4];
    tile[lc4 + 0][lr + i * 16] = v.x;
    tile[lc4 + 1][lr + i * 16] = v.y;
    tile[lc4 + 2][lr + i * 16] = v.z;
    tile[lc4 + 3][lr + i * 16] = v.w;
  }
  __syncthreads();
#pragma unroll
  for (int i = 0; i < 4; i++) {
    const int oc = (t >> 4) + i * 16;  // local out row (= in col)
    const int or4 = (t & 15) * 4;      // local out col (= in row)
    short4 o;
    o.x = f2b(tile[oc][or4 + 0]);
    o.y = f2b(tile[oc][or4 + 1]);
    o.z = f2b(tile[oc][or4 + 2]);
    o.w = f2b(tile[oc][or4 + 3]);
    const int c = c0 + oc;
    size_t orow;
    if (RMAP == 0) orow = bo + (size_t)c * R;
    else orow = (size_t)((c >> 5) * 64 + (RMAP == 2 ? 32 : 0) + (c & 31)) * R;
    *(short4*)&out[orow + r0 + or4] = o;
  }
}

// ---------------- router (wave per token, float4) ----------------
__global__ __launch_bounds__(256) void router_kernel(
    const float* __restrict__ x, const float* __restrict__ temb,
    const float* __restrict__ rw, const float* __restrict__ rbias,
    int* __restrict__ topk, float* __restrict__ gates) {
  const int t = (blockIdx.x * 256 + threadIdx.x) >> 6;
  const int lane = threadIdx.x & 63;
  const float* xr = x + (size_t)t * D_MODEL;
  const float* tr = temb + (size_t)(t >> 10) * D_MODEL;  // T=1024
  float acc[NEXP] = {};
#pragma unroll
  for (int i = 0; i < 4; i++) {
    const int j = i * 256 + lane * 4;
    const float4 xv = *(const float4*)&xr[j];
    const float4 tv = *(const float4*)&tr[j];
    const float* wx = rw + (size_t)j * NEXP;
    const float* wt = rw + (size_t)(D_MODEL + j) * NEXP;
    const float xa[4] = {xv.x, xv.y, xv.z, xv.w};
    const float ta[4] = {tv.x, tv.y, tv.z, tv.w};
#pragma unroll
    for (int u = 0; u < 4; u++)
#pragma unroll
      for (int e = 0; e < NEXP; e++)
        acc[e] += xa[u] * wx[u * NEXP + e] + ta[u] * wt[u * NEXP + e];
  }
#pragma unroll
  for (int off = 32; off; off >>= 1)
#pragma unroll
    for (int e = 0; e < NEXP; e++) acc[e] += __shfl_xor(acc[e], off);
  if (lane == 0) {
    float s[NEXP], sel[NEXP];
#pragma unroll
    for (int e = 0; e < NEXP; e++) {
      s[e] = 1.f / (1.f + expf(-acc[e]));
      sel[e] = s[e] + rbias[e];
    }
    int i0 = 0;
#pragma unroll
    for (int e = 1; e < NEXP; e++) if (sel[e] > sel[i0]) i0 = e;
    int i1 = (i0 == 0) ? 1 : 0;
#pragma unroll
    for (int e = 0; e < NEXP; e++) if (e != i0 && sel[e] > sel[i1]) i1 = e;
    float s0 = s[i0], s1 = s[i1], den = s0 + s1;
    float g0, g1;
    if (den > 1e-9f) { g0 = s0 / (den + 1e-9f); g1 = s1 / (den + 1e-9f); }
    else { g0 = 0.5f; g1 = 0.5f; }
    topk[t * 2] = i0; topk[t * 2 + 1] = i1;
    gates[t * 2] = g0; gates[t * 2 + 1] = g1;
  }
}

// ---------------- grouping: hist + scan + fill in one block ----------------
__global__ __launch_bounds__(1024) void group_kernel(const int* __restrict__ topk,
                                                     int* __restrict__ perm,
                                                     int* __restrict__ offs) {
  __shared__ int cnt[NEXP], cur[NEXP];
  const int t = threadIdx.x;
  if (t < NEXP) cnt[t] = 0;
  __syncthreads();
  int mye[8];
#pragma unroll
  for (int i = 0; i < 8; i++) {
    mye[i] = topk[i * 1024 + t];
    atomicAdd(&cnt[mye[i]], 1);
  }
  __syncthreads();
  if (t == 0) {
    int a = 0;
    for (int e = 0; e < NEXP; e++) { offs[e] = a; cur[e] = a; a += cnt[e]; }
    offs[NEXP] = a;
  }
  __syncthreads();
#pragma unroll
  for (int i = 0; i < 8; i++) {
    int pos = atomicAdd(&cur[mye[i]], 1);
    perm[pos] = i * 1024 + t;
  }
}

// ================= 256x256 BK=64 8-wave pipelined GEMM =================
// MODE 0 (G1): A=xb dense, B=w13I (w1/w3 interleaved 32-row groups), K=1024,
//              epilogue silu(a)*b -> u bf16 [NTOK][HS]. grid(16,16).
// MODE 1: A=xb gathered via perm>>1, B=W1eT[e], GELU -> hexpb[gi]. grid(4,32,8).
// MODE 2: A=hexpb dense slot-order, B=W2eT[e], gate*scatter -> yb[slot]. grid(4,32,8).
// LDS 128KiB: [buf2][op2][half2][64x128-row linear, XOR-swizzled data].
// NOTE: __launch_bounds__(512, 1): LDS already limits to 1 block/CU; asking for
// 2 blocks/CU capped VGPR at 128 (= acc alone) and spilled the K-loop to
// scratch (R3: MfmaUtil 8.6%, 82us). Cap 256 VGPR -> no spills.
template <int MODE>
__global__ __launch_bounds__(512, 1) void moe8ph(
    const short* __restrict__ A, const short* __restrict__ B, short* __restrict__ Cout,
    const int* __restrict__ perm, const int* __restrict__ offs,
    const float* __restrict__ gates) {
  extern __shared__ short lds[];
  const int td = threadIdx.x;
  const int bx = blockIdx.x;
  const int m0 = blockIdx.y * 256;
  int rbeg = 0, rend = 0;
  const short* Bbase;
  if (MODE == 0) {
    Bbase = B + (size_t)bx * 256 * 1024;
  } else {
    const int e = blockIdx.z;
    rbeg = offs[e]; rend = offs[e + 1];
    if (m0 >= rend - rbeg) return;
    Bbase = B + ((size_t)e * 1024 + bx * 256) * 1024;
  }

  // ---- per-thread stage source pointers (global pre-swizzled col) ----
  const int srow = td >> 3;
  const int colsw8 = ((td & 7) ^ (srow & 7)) * 8;
  const short* ap[2][2];
  const short* bp[2][2];
#pragma unroll
  for (int h = 0; h < 2; h++)
#pragma unroll
    for (int i = 0; i < 2; i++) {
      const int trow = h * 128 + i * 64 + srow;
      int grow;
      if (MODE == 0) grow = m0 + trow;
      else if (MODE == 1) grow = perm[min(rbeg + m0 + trow, rend - 1)] >> 1;
      else grow = min(rbeg + m0 + trow, rend - 1);
      ap[h][i] = A + (size_t)grow * 1024 + colsw8;
      bp[h][i] = Bbase + (size_t)trow * 1024 + colsw8;
    }

#define STAGE(op_, h_, t_, b_)                                                   \
  do {                                                                           \
    gl_lds16(((op_) ? bp[h_][0] : ap[h_][0]) + (t_) * 64,                        \
             lds + (b_) * 32768 + (op_) * 16384 + (h_) * 8192 + td * 8);         \
    gl_lds16(((op_) ? bp[h_][1] : ap[h_][1]) + (t_) * 64,                        \
             lds + (b_) * 32768 + (op_) * 16384 + (h_) * 8192 + 4096 + td * 8);  \
  } while (0)

  // ---- wave / fragment geometry ----
  const int l = td & 63;
  const int wid = td >> 6;
  const int mh = wid >> 2;    // A-half (output rows mh*128..)
  const int wn4 = wid & 3;    // n-block (64 cols)
  const int lr = l & 15;
  const int bhsel = wn4 >> 1;        // B half
  const int bnr = (wn4 & 1) * 64;    // row base within B half
  const int swzk0 = ((0 + (l >> 4) * 16) ^ ((l & 7) << 4)) >> 1;   // shorts
  const int swzk1 = ((64 + (l >> 4) * 16) ^ ((l & 7) << 4)) >> 1;

#define LDA(mf_, swz_) (*(const bf16x8*)&Ah[(unsigned)(((mf_)*16 + lr) * 64) + (swz_)])
#define LDB(nf_, swz_) (*(const bf16x8*)&Bh[(unsigned)((bnr + (nf_)*16 + lr) * 64) + (swz_)])
#define MM4(mf_, a_)                                                               \
  acc[mf_][0] = __builtin_amdgcn_mfma_f32_16x16x32_bf16(a_, b0, acc[mf_][0], 0, 0, 0); \
  acc[mf_][1] = __builtin_amdgcn_mfma_f32_16x16x32_bf16(a_, b1, acc[mf_][1], 0, 0, 0); \
  acc[mf_][2] = __builtin_amdgcn_mfma_f32_16x16x32_bf16(a_, b2, acc[mf_][2], 0, 0, 0); \
  acc[mf_][3] = __builtin_amdgcn_mfma_f32_16x16x32_bf16(a_, b3, acc[mf_][3], 0, 0, 0)

  f32x4 acc[8][4] = {};

  // prologue: stage tile 0 into buf 0 (8 loads outstanding)
  STAGE(0, 0, 0, 0); STAGE(0, 1, 0, 0); STAGE(1, 0, 0, 0); STAGE(1, 1, 0, 0);

#define ITER(t_, cur_, nxt_)                                                     \
  do {                                                                           \
    const short* Ah = lds + (cur_)*32768 + mh * 8192;                            \
    const short* Bh = lds + (cur_)*32768 + 16384 + bhsel * 8192;                 \
    if ((t_) + 1 < 16) {                                                         \
      STAGE(0, 0, (t_) + 1, nxt_);                                               \
      asm volatile("s_waitcnt vmcnt(2)" ::: "memory");                           \
    } else {                                                                     \
      asm volatile("s_waitcnt vmcnt(0)" ::: "memory");                           \
    }                                                                            \
    __builtin_amdgcn_s_barrier();                                                \
    __builtin_amdgcn_sched_barrier(0);                                           \
    bf16x8 b0 = LDB(0, swzk0), b1 = LDB(1, swzk0), b2 = LDB(2, swzk0),           \
           b3 = LDB(3, swzk0);                                                   \
    bf16x8 a0 = LDA(0, swzk0), a1 = LDA(1, swzk0), a2 = LDA(2, swzk0),           \
           a3 = LDA(3, swzk0);                                                   \
    __builtin_amdgcn_s_setprio(1);                                               \
    MM4(0, a0); MM4(1, a1); MM4(2, a2); MM4(3, a3);                              \
    __builtin_amdgcn_s_setprio(0);                                               \
    if ((t_) + 1 < 16) STAGE(0, 1, (t_) + 1, nxt_);                              \
    a0 = LDA(4, swzk0); a1 = LDA(5, swzk0); a2 = LDA(6, swzk0);                  \
    a3 = LDA(7, swzk0);                                                          \
    __builtin_amdgcn_s_setprio(1);                                               \
    MM4(4, a0); MM4(5, a1); MM4(6, a2); MM4(7, a3);                              \
    __builtin_amdgcn_s_setprio(0);                                               \
    if ((t_) + 1 < 16) STAGE(1, 0, (t_) + 1, nxt_);                              \
    b0 = LDB(0, swzk1); b1 = LDB(1, swzk1); b2 = LDB(2, swzk1);                  \
    b3 = LDB(3, swzk1);                                                          \
    a0 = LDA(0, swzk1); a1 = LDA(1, swzk1); a2 = LDA(2, swzk1);                  \
    a3 = LDA(3, swzk1);                                                          \
    __builtin_amdgcn_s_setprio(1);                                               \
    MM4(0, a0); MM4(1, a1); MM4(2, a2); MM4(3, a3);                              \
    __builtin_amdgcn_s_setprio(0);                                               \
    if ((t_) + 1 < 16) STAGE(1, 1, (t_) + 1, nxt_);                              \
    a0 = LDA(4, swzk1); a1 = LDA(5, swzk1); a2 = LDA(6, swzk1);                  \
    a3 = LDA(7, swzk1);                                                          \
    __builtin_amdgcn_s_setprio(1);                                               \
    MM4(4, a0); MM4(5, a1); MM4(6, a2); MM4(7, a3);                              \
    __builtin_amdgcn_s_setprio(0);                                               \
    asm volatile("s_waitcnt lgkmcnt(0)" ::: "memory");                           \
    __builtin_amdgcn_sched_barrier(0);                                           \
    __builtin_amdgcn_s_barrier();                                                \
  } while (0)

  for (int tt = 0; tt < 16; tt += 2) {
    ITER(tt, 0, 1);
    ITER(tt + 1, 1, 0);
  }

  // ---- epilogue ----
  const int rsub = (l >> 4) * 4;
  if (MODE == 0) {
#pragma unroll
    for (int mf = 0; mf < 8; mf++)
#pragma unroll
      for (int j = 0; j < 4; j++) {
        const int row = m0 + mh * 128 + mf * 16 + rsub + j;
        short* Up = Cout + (size_t)row * HS + bx * 128 + wn4 * 32 + lr;
#pragma unroll
        for (int nfp = 0; nfp < 2; nfp++) {
          const float a = acc[mf][nfp][j];
          const float b = acc[mf][nfp + 2][j];
          Up[nfp * 16] = f2b(a / (1.f + expf(-a)) * b);
        }
      }
  } else if (MODE == 1) {
#pragma unroll
    for (int mf = 0; mf < 8; mf++)
#pragma unroll
      for (int j = 0; j < 4; j++) {
        const int gi = rbeg + m0 + mh * 128 + mf * 16 + rsub + j;
        if (gi < rend) {
          short* Cp = Cout + (size_t)gi * HE + bx * 256 + wn4 * 64 + lr;
#pragma unroll
          for (int nf = 0; nf < 4; nf++) {
            const float v = acc[mf][nf][j];
            Cp[nf * 16] = f2b(0.5f * v * (1.0f + erff(v * 0.70710678118654752f)));
          }
        }
      }
  } else {
#pragma unroll
    for (int mf = 0; mf < 8; mf++)
#pragma unroll
      for (int j = 0; j < 4; j++) {
        const int gi = rbeg + m0 + mh * 128 + mf * 16 + rsub + j;
        if (gi < rend) {
          const int slot = perm[gi];
          const float g = gates[slot];
          short* Cp = Cout + (size_t)slot * D_MODEL + bx * 256 + wn4 * 64 + lr;
#pragma unroll
          for (int nf = 0; nf < 4; nf++) Cp[nf * 16] = f2b(g * acc[mf][nf][j]);
        }
      }
  }
#undef ITER
#undef STAGE
#undef LDA
#undef LDB
#undef MM4
}

// ---------------- G2: shared = u @ w2, fused final combine (2-phase 128²) ----------------
__global__ __launch_bounds__(256, 2) void gemm_g2(
    const short* __restrict__ A, const short* __restrict__ B,
    const short* __restrict__ yb, float* __restrict__ out) {
  __shared__ __align__(16) short As[4096];
  __shared__ __align__(16) short Bs[4096];
  const int t = threadIdx.x;
  const int tile_n = blockIdx.x * 128;  // over D_MODEL
  const int m0 = blockIdx.y * 128;
  const int r = t >> 2;
  const int c8 = (t & 3) * 8;
  const short* Ap0 = A + (size_t)(m0 + r) * HS + c8;
  const short* Ap1 = A + (size_t)(m0 + 64 + r) * HS + c8;
  const short* Bp0 = B + (size_t)(tile_n + r) * HS + c8;
  const short* Bp1 = B + (size_t)(tile_n + 64 + r) * HS + c8;

  const int lane = t & 63, wv = t >> 6;
  const int wm = (wv >> 1) * 64, wn = (wv & 1) * 64;
  const int lr = lane & 15, lk = (lane >> 4) * 8;

  f32x4 acc[4][4] = {};
  for (int k0 = 0; k0 < HS; k0 += 32) {
    gl_lds16(Ap0 + k0, &As[t * 8]);
    gl_lds16(Ap1 + k0, &As[2048 + t * 8]);
    gl_lds16(Bp0 + k0, &Bs[t * 8]);
    gl_lds16(Bp1 + k0, &Bs[2048 + t * 8]);
    __syncthreads();
    bf16x8 af[4], bfr[4];
#pragma unroll
    for (int m = 0; m < 4; m++) af[m] = *(const bf16x8*)&As[(wm + m * 16 + lr) * 32 + lk];
#pragma unroll
    for (int n = 0; n < 4; n++) bfr[n] = *(const bf16x8*)&Bs[(wn + n * 16 + lr) * 32 + lk];
#pragma unroll
    for (int m = 0; m < 4; m++)
#pragma unroll
      for (int n = 0; n < 4; n++)
        acc[m][n] = __builtin_amdgcn_mfma_f32_16x16x32_bf16(af[m], bfr[n], acc[m][n], 0, 0, 0);
    __syncthreads();
  }

  const int rq = (lane >> 4) * 4;
  const float inv3 = 1.0f / 3.0f;
#pragma unroll
  for (int m = 0; m < 4; m++) {
#pragma unroll
    for (int j = 0; j < 4; j++) {
      const int tok = m0 + wm + m * 16 + rq + j;
      const int colb = tile_n + wn + lr;
      const short* y0p = yb + (size_t)(tok * 2) * D_MODEL + colb;
      const short* y1p = yb + (size_t)(tok * 2 + 1) * D_MODEL + colb;
      float* Op = out + (size_t)tok * D_MODEL + colb;
#pragma unroll
      for (int n = 0; n < 4; n++) {
        Op[n * 16] = (acc[m][n][j] + b2f(y0p[n * 16]) + b2f(y1p[n * 16])) * inv3;
      }
    }
  }
}

// ---------------- launch ----------------
extern "C" void kernel_launch(void* const* d_in, const int* in_sizes, int n_in,
                              void* d_out, int out_size, void* d_ws, size_t ws_size,
                              hipStream_t stream) {
  const float* x = (const float*)d_in[0];
  const float* temb = (const float*)d_in[1];
  const float* rw = (const float*)d_in[2];
  const float* rbias = (const float*)d_in[3];
  const float* w1 = (const float*)d_in[4];
  const float* w3 = (const float*)d_in[5];
  const float* w2 = (const float*)d_in[6];
  const float* W1e = (const float*)d_in[7];
  const float* W2e = (const float*)d_in[8];
  float* out = (float*)d_out;

  const size_t MB = 1ull << 20;
  char* w = (char*)d_ws;
  short* xb    = (short*)(w + 0 * MB);    // 8 MB  [4096][1024]
  short* w13I  = (short*)(w + 8 * MB);    // 8 MB  [4096][1024] interleaved w1/w3
  short* w2T   = (short*)(w + 16 * MB);   // 4 MB  [1024][2048]
  short* W1eT  = (short*)(w + 20 * MB);   // 16 MB [8][1024][1024]
  short* W2eT  = (short*)(w + 36 * MB);   // 16 MB [8][1024][1024]
  short* ubuf  = (short*)(w + 52 * MB);   // 16 MB [4096][2048]
  short* hexpb = (short*)(w + 68 * MB);   // 16 MB [8192][1024]
  short* yb    = (short*)(w + 84 * MB);   // 16 MB [8192][1024] gated bf16
  float* gates = (float*)(w + 100 * MB);  // 32 KB
  int* topk    = (int*)(w + 100 * MB + 32 * 1024);
  int* perm    = (int*)(w + 100 * MB + 64 * 1024);
  int* offs    = (int*)(w + 100 * MB + 96 * 1024);

  // raise dynamic-LDS cap for the 128 KiB kernels (idempotent, host-side)
  hipFuncSetAttribute((const void*)&moe8ph<0>,
                      hipFuncAttributeMaxDynamicSharedMemorySize, 131072);
  hipFuncSetAttribute((const void*)&moe8ph<1>,
                      hipFuncAttributeMaxDynamicSharedMemorySize, 131072);
  hipFuncSetAttribute((const void*)&moe8ph<2>,
                      hipFuncAttributeMaxDynamicSharedMemorySize, 131072);

  // converts / transposes
  cvt_x_kernel<<<NTOK * D_MODEL / 4 / 256, 256, 0, stream>>>(x, xb);
  transpose_cvt<1><<<dim3(HS / 64, D_MODEL / 64, 1), 256, 0, stream>>>(w1, w13I, D_MODEL, HS);
  transpose_cvt<2><<<dim3(HS / 64, D_MODEL / 64, 1), 256, 0, stream>>>(w3, w13I, D_MODEL, HS);
  transpose_cvt<0><<<dim3(D_MODEL / 64, HS / 64, 1), 256, 0, stream>>>(w2, w2T, HS, D_MODEL);
  transpose_cvt<0><<<dim3(HE / 64, D_MODEL / 64, NEXP), 256, 0, stream>>>(W1e, W1eT, D_MODEL, HE);
  transpose_cvt<0><<<dim3(D_MODEL / 64, HE / 64, NEXP), 256, 0, stream>>>(W2e, W2eT, HE, D_MODEL);

  // router + grouping
  router_kernel<<<NTOK / 4, 256, 0, stream>>>(x, temb, rw, rbias, topk, gates);
  group_kernel<<<1, 1024, 0, stream>>>(topk, perm, offs);

  // G1: u = silu(x@w1)*(x@w3)  (8-phase 256², full 256-block fill)
  moe8ph<0><<<dim3(HS / 128, NTOK / 256, 1), 512, 131072, stream>>>(
      xb, w13I, ubuf, nullptr, nullptr, nullptr);

  // routed experts
  moe8ph<1><<<dim3(HE / 256, 32, NEXP), 512, 131072, stream>>>(
      xb, W1eT, hexpb, perm, offs, gates);
  moe8ph<2><<<dim3(D_MODEL / 256, 32, NEXP), 512, 131072, stream>>>(
      hexpb, W2eT, yb, perm, offs, gates);

  // shared down-proj + final combine
  gemm_g2<<<dim3(D_MODEL / 128, NTOK / 128, 1), 256, 0, stream>>>(ubuf, w2T, yb, out);
}

// Round 5
// 252.081 us; speedup vs baseline: 1.1786x; 1.1786x over previous
//
#include <hip/hip_runtime.h>
#include <hip/hip_bf16.h>
#include <math.h>

#define D_MODEL 1024
#define HS 2048
#define HE 1024
#define NEXP 8
#define NTOK 4096
#define NSLOT 8192

typedef __attribute__((ext_vector_type(4))) float f32x4;
typedef __attribute__((ext_vector_type(8))) short bf16x8;

__device__ __forceinline__ short f2b(float f) {
  __hip_bfloat16 h = __float2bfloat16(f);
  return *reinterpret_cast<short*>(&h);
}
__device__ __forceinline__ float b2f(short s) {
  return __bfloat162float(*reinterpret_cast<__hip_bfloat16*>(&s));
}

__device__ __forceinline__ void gl_lds16(const short* g, short* l) {
  __builtin_amdgcn_global_load_lds(
      (const __attribute__((address_space(1))) void*)g,
      (__attribute__((address_space(3))) void*)l, 16, 0, 0);
}

// ---------------- converts ----------------
__global__ __launch_bounds__(256) void cvt_x_kernel(const float* __restrict__ in,
                                                    short* __restrict__ out) {
  int i = blockIdx.x * 256 + threadIdx.x;  // over NTOK*D/4
  const float4 v = ((const float4*)in)[i];
  short4 o;
  o.x = f2b(v.x); o.y = f2b(v.y); o.z = f2b(v.z); o.w = f2b(v.w);
  ((short4*)out)[i] = o;
}

// in [R][C] f32 -> out bf16 transposed. RMAP: 0 plain [C][R]; 1/2: w13I
// interleaved row remap: out_row = (c>>5)*64 + (RMAP==2?32:0) + (c&31).
template <int RMAP>
__global__ __launch_bounds__(256) void transpose_cvt(const float* __restrict__ in,
                                                     short* __restrict__ out,
                                                     int R, int C) {
  __shared__ float tile[64][69];  // tile[col][row]
  const int t = threadIdx.x;
  const int c0 = blockIdx.x * 64;
  const int r0 = blockIdx.y * 64;
  const size_t bo = (size_t)blockIdx.z * R * C;
  const int lr = t >> 4;          // 0..15
  const int lc4 = (t & 15) * 4;   // 0..60
#pragma unroll
  for (int i = 0; i < 4; i++) {
    const float4 v = *(const float4*)&in[bo + (size_t)(r0 + lr + i * 16) * C + c0 + lc4];
    tile[lc4 + 0][lr + i * 16] = v.x;
    tile[lc4 + 1][lr + i * 16] = v.y;
    tile[lc4 + 2][lr + i * 16] = v.z;
    tile[lc4 + 3][lr + i * 16] = v.w;
  }
  __syncthreads();
#pragma unroll
  for (int i = 0; i < 4; i++) {
    const int oc = (t >> 4) + i * 16;  // local out row (= in col)
    const int or4 = (t & 15) * 4;      // local out col (= in row)
    short4 o;
    o.x = f2b(tile[oc][or4 + 0]);
    o.y = f2b(tile[oc][or4 + 1]);
    o.z = f2b(tile[oc][or4 + 2]);
    o.w = f2b(tile[oc][or4 + 3]);
    const int c = c0 + oc;
    size_t orow;
    if (RMAP == 0) orow = bo + (size_t)c * R;
    else orow = (size_t)((c >> 5) * 64 + (RMAP == 2 ? 32 : 0) + (c & 31)) * R;
    *(short4*)&out[orow + r0 + or4] = o;
  }
}

// ---------------- router (wave per token, float4) ----------------
__global__ __launch_bounds__(256) void router_kernel(
    const float* __restrict__ x, const float* __restrict__ temb,
    const float* __restrict__ rw, const float* __restrict__ rbias,
    int* __restrict__ topk, float* __restrict__ gates) {
  const int t = (blockIdx.x * 256 + threadIdx.x) >> 6;
  const int lane = threadIdx.x & 63;
  const float* xr = x + (size_t)t * D_MODEL;
  const float* tr = temb + (size_t)(t >> 10) * D_MODEL;  // T=1024
  float acc[NEXP] = {};
#pragma unroll
  for (int i = 0; i < 4; i++) {
    const int j = i * 256 + lane * 4;
    const float4 xv = *(const float4*)&xr[j];
    const float4 tv = *(const float4*)&tr[j];
    const float* wx = rw + (size_t)j * NEXP;
    const float* wt = rw + (size_t)(D_MODEL + j) * NEXP;
    const float xa[4] = {xv.x, xv.y, xv.z, xv.w};
    const float ta[4] = {tv.x, tv.y, tv.z, tv.w};
#pragma unroll
    for (int u = 0; u < 4; u++)
#pragma unroll
      for (int e = 0; e < NEXP; e++)
        acc[e] += xa[u] * wx[u * NEXP + e] + ta[u] * wt[u * NEXP + e];
  }
#pragma unroll
  for (int off = 32; off; off >>= 1)
#pragma unroll
    for (int e = 0; e < NEXP; e++) acc[e] += __shfl_xor(acc[e], off);
  if (lane == 0) {
    float s[NEXP], sel[NEXP];
#pragma unroll
    for (int e = 0; e < NEXP; e++) {
      s[e] = 1.f / (1.f + expf(-acc[e]));
      sel[e] = s[e] + rbias[e];
    }
    int i0 = 0;
#pragma unroll
    for (int e = 1; e < NEXP; e++) if (sel[e] > sel[i0]) i0 = e;
    int i1 = (i0 == 0) ? 1 : 0;
#pragma unroll
    for (int e = 0; e < NEXP; e++) if (e != i0 && sel[e] > sel[i1]) i1 = e;
    float s0 = s[i0], s1 = s[i1], den = s0 + s1;
    float g0, g1;
    if (den > 1e-9f) { g0 = s0 / (den + 1e-9f); g1 = s1 / (den + 1e-9f); }
    else { g0 = 0.5f; g1 = 0.5f; }
    topk[t * 2] = i0; topk[t * 2 + 1] = i1;
    gates[t * 2] = g0; gates[t * 2 + 1] = g1;
  }
}

// ---------------- grouping: hist + scan + fill in one block ----------------
__global__ __launch_bounds__(1024) void group_kernel(const int* __restrict__ topk,
                                                     int* __restrict__ perm,
                                                     int* __restrict__ offs) {
  __shared__ int cnt[NEXP], cur[NEXP];
  const int t = threadIdx.x;
  if (t < NEXP) cnt[t] = 0;
  __syncthreads();
  int mye[8];
#pragma unroll
  for (int i = 0; i < 8; i++) {
    mye[i] = topk[i * 1024 + t];
    atomicAdd(&cnt[mye[i]], 1);
  }
  __syncthreads();
  if (t == 0) {
    int a = 0;
    for (int e = 0; e < NEXP; e++) { offs[e] = a; cur[e] = a; a += cnt[e]; }
    offs[NEXP] = a;
  }
  __syncthreads();
#pragma unroll
  for (int i = 0; i < 8; i++) {
    int pos = atomicAdd(&cur[mye[i]], 1);
    perm[pos] = i * 1024 + t;
  }
}

// ================= G1: 256x256 BK=64, faithful per-phase-barrier 8-wave =================
// u = silu(x@w1)*(x@w3). B = w13I (w1/w3 interleaved 32-row groups). K=1024.
// LDS 128KiB: 2 bufs x { A[256][64] | B[256][64] }, XOR-swizzled (st-style).
// Per K-tile, 4 phases, each: {ds_read 4-8 x b128; stage one 2-load unit;
//   [vmcnt at ph1/ph4]; barrier; lgkmcnt(0); sched_barrier; setprio(1);
//   16 MFMA; setprio(0); barrier; sched_barrier}.
// Stage units of tile t+1 in order {B0, B1, A.i0, A.i1}; vmcnt(2) at ph1-end
// guarantees prev A.i1 landed (needed ph2); vmcnt(2) at ph4-end guarantees
// B0,B1,A.i0 of t+1 (needed next ph1). Counter never drains in-loop.
__global__ __launch_bounds__(512, 1) void gemm_g1_8ph(
    const short* __restrict__ A, const short* __restrict__ B, short* __restrict__ U) {
  extern __shared__ short lds[];
  const int td = threadIdx.x;
  const int bx = blockIdx.x;   // B row-panel bx*256 (128 u-cols)
  const int m0 = blockIdx.y * 256;
  const short* Bbase = B + (size_t)bx * 256 * 1024;

  // staging source pointers (global col pre-swizzled, rule 21)
  const int srow = td >> 3;
  const int colsw8 = ((td & 7) ^ (srow & 7)) * 8;
  const short* ap[2][2];
  const short* bp[2][2];
#pragma unroll
  for (int h = 0; h < 2; h++)
#pragma unroll
    for (int i = 0; i < 2; i++) {
      const int trow = h * 128 + i * 64 + srow;
      ap[h][i] = A + (size_t)(m0 + trow) * 1024 + colsw8;
      bp[h][i] = Bbase + (size_t)trow * 1024 + colsw8;
    }

  // LDS dests (shorts): buf*32768 + op*16384 + h*8192 + i*4096 + td*8
#define SB0(t_, b_)                                                        \
  do {                                                                     \
    gl_lds16(bp[0][0] + (t_) * 64, lds + (b_) * 32768 + 16384 + td * 8);   \
    gl_lds16(bp[0][1] + (t_) * 64, lds + (b_) * 32768 + 16384 + 4096 + td * 8); \
  } while (0)
#define SB1(t_, b_)                                                        \
  do {                                                                     \
    gl_lds16(bp[1][0] + (t_) * 64, lds + (b_) * 32768 + 16384 + 8192 + td * 8); \
    gl_lds16(bp[1][1] + (t_) * 64, lds + (b_) * 32768 + 16384 + 8192 + 4096 + td * 8); \
  } while (0)
#define SAI0(t_, b_)                                                       \
  do {                                                                     \
    gl_lds16(ap[0][0] + (t_) * 64, lds + (b_) * 32768 + td * 8);           \
    gl_lds16(ap[1][0] + (t_) * 64, lds + (b_) * 32768 + 8192 + td * 8);    \
  } while (0)
#define SAI1(t_, b_)                                                       \
  do {                                                                     \
    gl_lds16(ap[0][1] + (t_) * 64, lds + (b_) * 32768 + 4096 + td * 8);    \
    gl_lds16(ap[1][1] + (t_) * 64, lds + (b_) * 32768 + 8192 + 4096 + td * 8); \
  } while (0)

  // wave / fragment geometry
  const int l = td & 63;
  const int wid = td >> 6;
  const int mh = wid >> 2;          // A half (output rows mh*128..)
  const int wn4 = wid & 3;          // 64-col block
  const int lr = l & 15;
  const int bhsel = wn4 >> 1;
  const int bnr = (wn4 & 1) * 64;
  const int swzk0 = ((0 + (l >> 4) * 16) ^ ((l & 7) << 4)) >> 1;   // shorts
  const int swzk1 = ((64 + (l >> 4) * 16) ^ ((l & 7) << 4)) >> 1;

#define LDA(mf_, swz_) (*(const bf16x8*)&Ah[(unsigned)(((mf_)*16 + lr) * 64) + (swz_)])
#define LDB(nf_, swz_) (*(const bf16x8*)&Bh[(unsigned)((bnr + (nf_)*16 + lr) * 64) + (swz_)])
#define MMROW(mf_, a_)                                                                 \
  acc[mf_][0] = __builtin_amdgcn_mfma_f32_16x16x32_bf16(a_, b0, acc[mf_][0], 0, 0, 0); \
  acc[mf_][1] = __builtin_amdgcn_mfma_f32_16x16x32_bf16(a_, b1, acc[mf_][1], 0, 0, 0); \
  acc[mf_][2] = __builtin_amdgcn_mfma_f32_16x16x32_bf16(a_, b2, acc[mf_][2], 0, 0, 0); \
  acc[mf_][3] = __builtin_amdgcn_mfma_f32_16x16x32_bf16(a_, b3, acc[mf_][3], 0, 0, 0)

#define PH_TAIL                                   \
  __builtin_amdgcn_s_barrier();                   \
  asm volatile("s_waitcnt lgkmcnt(0)" ::: "memory"); \
  __builtin_amdgcn_sched_barrier(0);              \
  __builtin_amdgcn_s_setprio(1)
#define PH_END                                    \
  __builtin_amdgcn_s_setprio(0);                  \
  __builtin_amdgcn_s_barrier();                   \
  __builtin_amdgcn_sched_barrier(0)

  f32x4 acc[8][4] = {};

  // prologue: tile 0 into buf 0, then allow only A.i1 in flight
  SB0(0, 0); SB1(0, 0); SAI0(0, 0); SAI1(0, 0);
  asm volatile("s_waitcnt vmcnt(2)" ::: "memory");
  __builtin_amdgcn_s_barrier();

  for (int t = 0; t < 16; ++t) {
    const int p = t & 1, q = p ^ 1;
    const short* Ah = lds + p * 32768 + mh * 8192;
    const short* Bh = lds + p * 32768 + 16384 + bhsel * 8192;
    bf16x8 b0, b1, b2, b3, a0, a1, a2, a3;
    // ---- ph1: mf0-3 @ k0 ----
    b0 = LDB(0, swzk0); b1 = LDB(1, swzk0); b2 = LDB(2, swzk0); b3 = LDB(3, swzk0);
    a0 = LDA(0, swzk0); a1 = LDA(1, swzk0); a2 = LDA(2, swzk0); a3 = LDA(3, swzk0);
    if (t < 15) {
      SB0(t + 1, q);
      asm volatile("s_waitcnt vmcnt(2)" ::: "memory");
    } else {
      asm volatile("s_waitcnt vmcnt(0)" ::: "memory");
    }
    PH_TAIL;
    MMROW(0, a0); MMROW(1, a1); MMROW(2, a2); MMROW(3, a3);
    PH_END;
    // ---- ph2: mf4-7 @ k0 (reuse b regs) ----
    a0 = LDA(4, swzk0); a1 = LDA(5, swzk0); a2 = LDA(6, swzk0); a3 = LDA(7, swzk0);
    if (t < 15) SB1(t + 1, q);
    PH_TAIL;
    MMROW(4, a0); MMROW(5, a1); MMROW(6, a2); MMROW(7, a3);
    PH_END;
    // ---- ph3: mf0-3 @ k1 ----
    b0 = LDB(0, swzk1); b1 = LDB(1, swzk1); b2 = LDB(2, swzk1); b3 = LDB(3, swzk1);
    a0 = LDA(0, swzk1); a1 = LDA(1, swzk1); a2 = LDA(2, swzk1); a3 = LDA(3, swzk1);
    if (t < 15) SAI0(t + 1, q);
    PH_TAIL;
    MMROW(0, a0); MMROW(1, a1); MMROW(2, a2); MMROW(3, a3);
    PH_END;
    // ---- ph4: mf4-7 @ k1 ----
    a0 = LDA(4, swzk1); a1 = LDA(5, swzk1); a2 = LDA(6, swzk1); a3 = LDA(7, swzk1);
    if (t < 15) {
      SAI1(t + 1, q);
      asm volatile("s_waitcnt vmcnt(2)" ::: "memory");
    }
    PH_TAIL;
    MMROW(4, a0); MMROW(5, a1); MMROW(6, a2); MMROW(7, a3);
    PH_END;
  }

  // ---- epilogue: silu(a)*b -> bf16 u ----
  const int rsub = (l >> 4) * 4;
#pragma unroll
  for (int mf = 0; mf < 8; mf++)
#pragma unroll
    for (int j = 0; j < 4; j++) {
      const int row = m0 + mh * 128 + mf * 16 + rsub + j;
      short* Up = U + (size_t)row * HS + bx * 128 + wn4 * 32 + lr;
#pragma unroll
      for (int nfp = 0; nfp < 2; nfp++) {
        const float a = acc[mf][nfp][j];
        const float b = acc[mf][nfp + 2][j];
        Up[nfp * 16] = f2b(a / (1.f + expf(-a)) * b);
      }
    }
#undef SB0
#undef SB1
#undef SAI0
#undef SAI1
#undef LDA
#undef LDB
#undef MMROW
#undef PH_TAIL
#undef PH_END
}

// ---------------- grouped GEMMs (proven 2-phase 128², R2 structure) ----------------
// MODE 1: gather A rows via perm>>1, exact-GELU epilogue -> bf16 rows at gi
// MODE 2: A dense in perm order, gate-scale + scatter bf16 rows via perm
template <int MODE>
__global__ __launch_bounds__(256, 2) void gemm_grouped(
    const short* __restrict__ A, const short* __restrict__ B, short* __restrict__ C,
    const int* __restrict__ perm, const int* __restrict__ offs,
    const float* __restrict__ gates) {
  __shared__ __align__(16) short As[4096];
  __shared__ __align__(16) short Bs[4096];
  const int t = threadIdx.x;
  const int tile_n = blockIdx.x * 128;
  const int m0 = blockIdx.y * 128;
  const int e = blockIdx.z;
  const int rbeg = offs[e], rend = offs[e + 1];
  if (m0 >= rend - rbeg) return;
  const int K = (MODE == 1) ? D_MODEL : HE;
  const short* Bp = B + (size_t)e * (size_t)HE * D_MODEL;

  const int r = t >> 2;
  const int c8 = (t & 3) * 8;
  size_t arow0, arow1;
  {
    int gi0 = min(rbeg + m0 + r, rend - 1);
    int gi1 = min(rbeg + m0 + 64 + r, rend - 1);
    if (MODE == 1) {
      arow0 = (size_t)(perm[gi0] >> 1) * K;
      arow1 = (size_t)(perm[gi1] >> 1) * K;
    } else {
      arow0 = (size_t)gi0 * K;
      arow1 = (size_t)gi1 * K;
    }
  }
  const short* Ap0 = A + arow0 + c8;
  const short* Ap1 = A + arow1 + c8;
  const short* Bp0 = Bp + (size_t)(tile_n + r) * K + c8;
  const short* Bp1 = Bp + (size_t)(tile_n + 64 + r) * K + c8;

  const int lane = t & 63, wv = t >> 6;
  const int wm = (wv >> 1) * 64, wn = (wv & 1) * 64;
  const int lr = lane & 15, lk = (lane >> 4) * 8;

  f32x4 acc[4][4] = {};
  for (int k0 = 0; k0 < K; k0 += 32) {
    gl_lds16(Ap0 + k0, &As[t * 8]);
    gl_lds16(Ap1 + k0, &As[2048 + t * 8]);
    gl_lds16(Bp0 + k0, &Bs[t * 8]);
    gl_lds16(Bp1 + k0, &Bs[2048 + t * 8]);
    __syncthreads();
    bf16x8 af[4], bfr[4];
#pragma unroll
    for (int m = 0; m < 4; m++) af[m] = *(const bf16x8*)&As[(wm + m * 16 + lr) * 32 + lk];
#pragma unroll
    for (int n = 0; n < 4; n++) bfr[n] = *(const bf16x8*)&Bs[(wn + n * 16 + lr) * 32 + lk];
#pragma unroll
    for (int m = 0; m < 4; m++)
#pragma unroll
      for (int n = 0; n < 4; n++)
        acc[m][n] = __builtin_amdgcn_mfma_f32_16x16x32_bf16(af[m], bfr[n], acc[m][n], 0, 0, 0);
    __syncthreads();
  }

  const int rq = (lane >> 4) * 4;
#pragma unroll
  for (int m = 0; m < 4; m++) {
#pragma unroll
    for (int j = 0; j < 4; j++) {
      const int gi = rbeg + m0 + wm + m * 16 + rq + j;
      if (gi < rend) {
        if (MODE == 1) {
          short* Cp = C + (size_t)gi * HE + tile_n + wn + lr;
#pragma unroll
          for (int n = 0; n < 4; n++) {
            float v = acc[m][n][j];
            Cp[n * 16] = f2b(0.5f * v * (1.0f + erff(v * 0.70710678118654752f)));
          }
        } else {
          const int slot = perm[gi];
          const float g = gates[slot];
          short* Cp = C + (size_t)slot * D_MODEL + tile_n + wn + lr;
#pragma unroll
          for (int n = 0; n < 4; n++) Cp[n * 16] = f2b(g * acc[m][n][j]);
        }
      }
    }
  }
}

// ---------------- G2: shared = u @ w2, fused final combine (2-phase 128²) ----------------
__global__ __launch_bounds__(256, 2) void gemm_g2(
    const short* __restrict__ A, const short* __restrict__ B,
    const short* __restrict__ yb, float* __restrict__ out) {
  __shared__ __align__(16) short As[4096];
  __shared__ __align__(16) short Bs[4096];
  const int t = threadIdx.x;
  const int tile_n = blockIdx.x * 128;  // over D_MODEL
  const int m0 = blockIdx.y * 128;
  const int r = t >> 2;
  const int c8 = (t & 3) * 8;
  const short* Ap0 = A + (size_t)(m0 + r) * HS + c8;
  const short* Ap1 = A + (size_t)(m0 + 64 + r) * HS + c8;
  const short* Bp0 = B + (size_t)(tile_n + r) * HS + c8;
  const short* Bp1 = B + (size_t)(tile_n + 64 + r) * HS + c8;

  const int lane = t & 63, wv = t >> 6;
  const int wm = (wv >> 1) * 64, wn = (wv & 1) * 64;
  const int lr = lane & 15, lk = (lane >> 4) * 8;

  f32x4 acc[4][4] = {};
  for (int k0 = 0; k0 < HS; k0 += 32) {
    gl_lds16(Ap0 + k0, &As[t * 8]);
    gl_lds16(Ap1 + k0, &As[2048 + t * 8]);
    gl_lds16(Bp0 + k0, &Bs[t * 8]);
    gl_lds16(Bp1 + k0, &Bs[2048 + t * 8]);
    __syncthreads();
    bf16x8 af[4], bfr[4];
#pragma unroll
    for (int m = 0; m < 4; m++) af[m] = *(const bf16x8*)&As[(wm + m * 16 + lr) * 32 + lk];
#pragma unroll
    for (int n = 0; n < 4; n++) bfr[n] = *(const bf16x8*)&Bs[(wn + n * 16 + lr) * 32 + lk];
#pragma unroll
    for (int m = 0; m < 4; m++)
#pragma unroll
      for (int n = 0; n < 4; n++)
        acc[m][n] = __builtin_amdgcn_mfma_f32_16x16x32_bf16(af[m], bfr[n], acc[m][n], 0, 0, 0);
    __syncthreads();
  }

  const int rq = (lane >> 4) * 4;
  const float inv3 = 1.0f / 3.0f;
#pragma unroll
  for (int m = 0; m < 4; m++) {
#pragma unroll
    for (int j = 0; j < 4; j++) {
      const int tok = m0 + wm + m * 16 + rq + j;
      const int colb = tile_n + wn + lr;
      const short* y0p = yb + (size_t)(tok * 2) * D_MODEL + colb;
      const short* y1p = yb + (size_t)(tok * 2 + 1) * D_MODEL + colb;
      float* Op = out + (size_t)tok * D_MODEL + colb;
#pragma unroll
      for (int n = 0; n < 4; n++) {
        Op[n * 16] = (acc[m][n][j] + b2f(y0p[n * 16]) + b2f(y1p[n * 16])) * inv3;
      }
    }
  }
}

// ---------------- launch ----------------
extern "C" void kernel_launch(void* const* d_in, const int* in_sizes, int n_in,
                              void* d_out, int out_size, void* d_ws, size_t ws_size,
                              hipStream_t stream) {
  const float* x = (const float*)d_in[0];
  const float* temb = (const float*)d_in[1];
  const float* rw = (const float*)d_in[2];
  const float* rbias = (const float*)d_in[3];
  const float* w1 = (const float*)d_in[4];
  const float* w3 = (const float*)d_in[5];
  const float* w2 = (const float*)d_in[6];
  const float* W1e = (const float*)d_in[7];
  const float* W2e = (const float*)d_in[8];
  float* out = (float*)d_out;

  const size_t MB = 1ull << 20;
  char* w = (char*)d_ws;
  short* xb    = (short*)(w + 0 * MB);    // 8 MB  [4096][1024]
  short* w13I  = (short*)(w + 8 * MB);    // 8 MB  [4096][1024] interleaved w1/w3
  short* w2T   = (short*)(w + 16 * MB);   // 4 MB  [1024][2048]
  short* W1eT  = (short*)(w + 20 * MB);   // 16 MB [8][1024][1024]
  short* W2eT  = (short*)(w + 36 * MB);   // 16 MB [8][1024][1024]
  short* ubuf  = (short*)(w + 52 * MB);   // 16 MB [4096][2048]
  short* hexpb = (short*)(w + 68 * MB);   // 16 MB [8192][1024]
  short* yb    = (short*)(w + 84 * MB);   // 16 MB [8192][1024] gated bf16
  float* gates = (float*)(w + 100 * MB);  // 32 KB
  int* topk    = (int*)(w + 100 * MB + 32 * 1024);
  int* perm    = (int*)(w + 100 * MB + 64 * 1024);
  int* offs    = (int*)(w + 100 * MB + 96 * 1024);

  hipFuncSetAttribute((const void*)&gemm_g1_8ph,
                      hipFuncAttributeMaxDynamicSharedMemorySize, 131072);

  // converts / transposes
  cvt_x_kernel<<<NTOK * D_MODEL / 4 / 256, 256, 0, stream>>>(x, xb);
  transpose_cvt<1><<<dim3(HS / 64, D_MODEL / 64, 1), 256, 0, stream>>>(w1, w13I, D_MODEL, HS);
  transpose_cvt<2><<<dim3(HS / 64, D_MODEL / 64, 1), 256, 0, stream>>>(w3, w13I, D_MODEL, HS);
  transpose_cvt<0><<<dim3(D_MODEL / 64, HS / 64, 1), 256, 0, stream>>>(w2, w2T, HS, D_MODEL);
  transpose_cvt<0><<<dim3(HE / 64, D_MODEL / 64, NEXP), 256, 0, stream>>>(W1e, W1eT, D_MODEL, HE);
  transpose_cvt<0><<<dim3(D_MODEL / 64, HE / 64, NEXP), 256, 0, stream>>>(W2e, W2eT, HE, D_MODEL);

  // router + grouping
  router_kernel<<<NTOK / 4, 256, 0, stream>>>(x, temb, rw, rbias, topk, gates);
  group_kernel<<<1, 1024, 0, stream>>>(topk, perm, offs);

  // G1: u = silu(x@w1)*(x@w3)  (faithful 8-phase 256²)
  gemm_g1_8ph<<<dim3(HS / 128, NTOK / 256, 1), 512, 131072, stream>>>(xb, w13I, ubuf);

  // routed experts (2-phase 128² hedge)
  gemm_grouped<1><<<dim3(HE / 128, NSLOT / 128, NEXP), 256, 0, stream>>>(
      xb, W1eT, hexpb, perm, offs, gates);
  gemm_grouped<2><<<dim3(D_MODEL / 128, NSLOT / 128, NEXP), 256, 0, stream>>>(
      hexpb, W2eT, yb, perm, offs, gates);

  // shared down-proj + final combine
  gemm_g2<<<dim3(D_MODEL / 128, NTOK / 128, 1), 256, 0, stream>>>(ubuf, w2T, yb, out);
}